// Round 2
// baseline (270.651 us; speedup 1.0000x reference)
//
#include <hip/hip_runtime.h>
#include <math.h>

#define ED      256       // EMBED_DIM
#define NL      4
#define NH      8
#define NP      4
#define HD      32        // HEAD_DIM
#define HMAX    128
#define WMAX    128
#define NLP     16        // NL*NP
#define NC      128       // NL*NP*NH
#define NOFF_AW 384       // 256 off cols + 128 attn cols
#define QPB     8         // queries per block in sampler (1 wave/query)
#define BSTRIDE (HMAX*WMAX*NL*ED)   // 16,777,216 elements
#define XSTRIDE (WMAX*NL*ED)        // 131,072
#define YSTRIDE (NL*ED)             // 1,024
#define RPB     21760               // compact rows per batch: 128^2+64^2+32^2+16^2
#define PBC     (RPB*256)           // compact elems per batch

typedef __attribute__((ext_vector_type(8))) __fp16   f16x8;
typedef __attribute__((ext_vector_type(4))) __fp16   f16x4;
typedef __attribute__((ext_vector_type(4))) float    f32x4;

__constant__ int LBASE_ROW[4] = {0, 16384, 20480, 21504};

// ---------------- Kprep: V compaction into HEAD-MAJOR f16 layout ----------
// Vc[b][level l][head h][x*sz + y][32 dims] -- 64-B rows; (x,y) and (x,y+1)
// contiguous 128 B so a bilinear y-pair is one segment.
// + weight transpose/convert.
__global__ __launch_bounds__(1024) void msda_prep_kernel(
    const float* __restrict__ V,
    const float* __restrict__ W_off,
    const float* __restrict__ W_attn,
    const float* __restrict__ W_out,
    __fp16* __restrict__ Vc,
    __fp16* __restrict__ WcatT,
    __fp16* __restrict__ WoutT,
    int nb, int nCompact)
{
    const int bid = blockIdx.x;
    const int t   = threadIdx.x;

    if (bid < nCompact) {
        const int r    = bid * 16 + (t >> 6);
        const int lane = t & 63;
        const int h    = lane >> 3;
        const int j4   = lane & 7;
        const int total_rows = nb * RPB;
        if (r < total_rows) {
            const int b  = r / RPB;
            const int rr = r - b * RPB;
            int l;
            if (rr < 16384)      { l = 0; }
            else if (rr < 20480) { l = 1; }
            else if (rr < 21504) { l = 2; }
            else                 { l = 3; }
            const int pos = rr - LBASE_ROW[l];    // x*sz + y within level
            const int lsh = 7 - l;
            const int xi  = pos >> lsh;
            const int yi  = pos & ((1 << lsh) - 1);
            const int plane32 = (1 << (2 * lsh)) * 32;   // per-head plane elems
            const float4 src = *(const float4*)&V[(size_t)b * BSTRIDE +
                (size_t)xi * XSTRIDE + (size_t)yi * YSTRIDE + l * ED +
                h * HD + j4 * 4];
            f16x4 d;
            d[0] = (__fp16)src.x; d[1] = (__fp16)src.y;
            d[2] = (__fp16)src.z; d[3] = (__fp16)src.w;
            const size_t dst = (size_t)b * PBC + (size_t)LBASE_ROW[l] * 256 +
                               (size_t)h * plane32 + (size_t)pos * 32 + j4 * 4;
            *(f16x4*)&Vc[dst] = d;
        }
    } else {
        const int idx = (bid - nCompact) * 1024 + t;
        const int t2 = NOFF_AW * ED;
        const int t3 = ED * ED;
        if (idx < t2) {
            int c = idx >> 8, e = idx & 255;
            float v = (c < ED) ? W_off[e * ED + c] : W_attn[e * NC + (c - ED)];
            WcatT[idx] = (__fp16)v;
        } else if (idx < t2 + t3) {
            int i = idx - t2;
            int c = i >> 8, e = i & 255;
            WoutT[i] = (__fp16)W_out[e * ED + c];
        }
    }
}

// ---- K2: FUSED offset/attn GEMM + softmax + sampling + paired bilinear ---
// ---- gather + out-projection. One launch, no off_aw / out_pre round trip.
// QPB=8 queries/block, 512 threads (8 waves).
// Phase 1: [off|aw](16x384) = q @ WcatT^T + bias via MFMA -> LDS (u.offaw).
// Phase 2: softmax stats + ref prep.  Phase 3: sampling params.
// Phase 4: gather -> LDS tile (u.sout, union'd over dead offaw).
// Phase 5: out = sout @ WoutT^T + b_out via MFMA -> global f32.
__global__ __launch_bounds__(512, 6) void msda_sample_kernel(
    const float*  __restrict__ refp,     // (Q, 2)
    const __fp16* __restrict__ Vc,       // compact head-major f16 V
    const float*  __restrict__ query,    // (Q, 256) f32
    const __fp16* __restrict__ WcatT,    // (384,256) f16, row n = [Woff|Wattn][:,n]
    const float*  __restrict__ b_off,
    const float*  __restrict__ b_attn,
    const int*    __restrict__ batch_off,
    int n_batch,
    const __fp16* __restrict__ WoutT,    // (256,256) f16, row n = W_out[:,n]
    const float*  __restrict__ b_out,
    float* __restrict__ out,             // (Q, 256) f32
    int q_total)
{
    // offaw (12.3 KB) is dead after phase 3; sout (8.4 KB) lives in phases
    // 4-5 -> union keeps the block at 37.4 KB LDS (4 blocks/CU budget).
    __shared__ __attribute__((aligned(16))) union {
        float  offaw[QPB][NOFF_AW];      // phases 1-3
        __fp16 sout[16][ED + 8];         // phases 4-5 (+8 pad: bank rotate)
    } u;
    __shared__ float2 sminv[QPB][NH];
    __shared__ float2 sref[QPB];
    __shared__ int2   soff[QPB][NC];     // pairA (x0), pairB (x1) elem offsets
    __shared__ float4 swt[QPB][NC];      // folded w00,w01,w10,w11

    const int t  = threadIdx.x;
    const int q0 = blockIdx.x * QPB;
    const int w    = t >> 6;             // wave id 0..7
    const int lane = t & 63;

    // ---- phase 1: in-block GEMM: u.offaw[0..7][0..383] ----
    // 16x384, K=256, 2-pass f16 (A exact). Wave w owns 48 output cols.
    {
        const int mrow = lane & 15;
        const int quad = lane >> 4;
        // A rows 8..15 alias 0..7 (results discarded; avoids neighbor reads)
        const int arow = q0 + (mrow & 7);
        const float4* Arow = (const float4*)(query + (size_t)arow * 256 + quad * 8);
        const int nbase = w * 48;
        const f16x8* B0 = (const f16x8*)(WcatT + (size_t)(nbase +  0 + mrow) * 256 + quad * 8);
        const f16x8* B1 = (const f16x8*)(WcatT + (size_t)(nbase + 16 + mrow) * 256 + quad * 8);
        const f16x8* B2 = (const f16x8*)(WcatT + (size_t)(nbase + 32 + mrow) * 256 + quad * 8);

        f32x4 acc0 = {0.f,0.f,0.f,0.f}, acc1 = acc0, acc2 = acc0;
        #pragma unroll
        for (int kb = 0; kb < 8; ++kb) {
            float4 a0 = Arow[kb * 8 + 0];
            float4 a1 = Arow[kb * 8 + 1];
            float av[8] = {a0.x, a0.y, a0.z, a0.w, a1.x, a1.y, a1.z, a1.w};
            f16x8 ah, al;
            #pragma unroll
            for (int j = 0; j < 8; ++j) {
                __fp16 hh = (__fp16)av[j];
                ah[j] = hh;
                al[j] = (__fp16)(av[j] - (float)hh);
            }
            f16x8 b0 = B0[kb * 4], b1 = B1[kb * 4], b2 = B2[kb * 4];
            acc0 = __builtin_amdgcn_mfma_f32_16x16x32_f16(ah, b0, acc0, 0, 0, 0);
            acc1 = __builtin_amdgcn_mfma_f32_16x16x32_f16(ah, b1, acc1, 0, 0, 0);
            acc2 = __builtin_amdgcn_mfma_f32_16x16x32_f16(ah, b2, acc2, 0, 0, 0);
            acc0 = __builtin_amdgcn_mfma_f32_16x16x32_f16(al, b0, acc0, 0, 0, 0);
            acc1 = __builtin_amdgcn_mfma_f32_16x16x32_f16(al, b1, acc1, 0, 0, 0);
            acc2 = __builtin_amdgcn_mfma_f32_16x16x32_f16(al, b2, acc2, 0, 0, 0);
        }
        const int col = lane & 15;
        f32x4 accs[3] = {acc0, acc1, acc2};
        #pragma unroll
        for (int i = 0; i < 3; ++i) {
            int n = nbase + i * 16 + col;
            float bb = (n < ED) ? b_off[n] : b_attn[n - ED];
            #pragma unroll
            for (int r = 0; r < 4; ++r) {
                int row = quad * 4 + r;
                if (row < QPB)
                    u.offaw[row][n] = accs[i][r] + bb;
            }
        }
    }
    __syncthreads();

    // ---- phase 2: softmax stats + ref-point prep ----
    if (t < QPB * NH) {
        const int s = t >> 3, h = t & 7;
        float m = -1e30f;
        #pragma unroll
        for (int lp = 0; lp < NLP; ++lp)
            m = fmaxf(m, u.offaw[s][ED + lp * NH + h]);
        float sum = 0.f;
        #pragma unroll
        for (int lp = 0; lp < NLP; ++lp)
            sum += __expf(u.offaw[s][ED + lp * NH + h] - m);
        sminv[s][h] = make_float2(m, 1.f / sum);
    } else if (t < QPB * NH + QPB) {
        const int s = t - QPB * NH;
        const int qid = q0 + s;
        float rx = refp[qid * 2 + 0], ry = refp[qid * 2 + 1];
        rx = fminf(fmaxf(rx, 0.f), 1.f);
        ry = fminf(fmaxf(ry, 0.f), 1.f);
        float ivx = __logf(fmaxf(rx, 1e-5f) / fmaxf(1.f - rx, 1e-5f));
        float ivy = __logf(fmaxf(ry, 1e-5f) / fmaxf(1.f - ry, 1e-5f));
        sref[s] = make_float2(ivx, ivy);
    }
    __syncthreads();

    // ---- phase 3: sampling params: pair offsets + folded weights ----
    {
        const int s = w;
        const int qid = q0 + s;
        int b = 0;
        for (int i = 1; i < n_batch; ++i)
            if (batch_off[i] <= qid) b = i;
        const int cb = b * PBC;
        const float2 iv = sref[s];
        const float* offrow = u.offaw[s];

        #pragma unroll
        for (int half = 0; half < 2; ++half) {
            const int c = lane + half * 64;
            const int l = c >> 5;
            const int lsh = 7 - l;
            const int sz  = 1 << lsh;
            const int cap = sz - 1;
            const int h = c & 7;
            const int plane32 = (sz * sz) << 5;

            const float2 mi = sminv[s][h];
            const float a = __expf(offrow[ED + c] - mi.x) * mi.y;

            const float ox = offrow[c * 2 + 0], oy = offrow[c * 2 + 1];
            float lx = 2.f / (1.f + __expf(-(iv.x + ox))) - 1.f;
            float ly = 2.f / (1.f + __expf(-(iv.y + oy))) - 1.f;
            float x = ((lx + 1.f) * (float)sz - 1.f) * 0.5f;
            float y = ((ly + 1.f) * (float)sz - 1.f) * 0.5f;
            int x0 = (int)floorf(x), y0 = (int)floorf(y);
            int x1 = x0 + 1, y1 = y0 + 1;
            x0 = min(max(x0, 0), cap); x1 = min(max(x1, 0), cap);
            y0 = min(max(y0, 0), cap); y1 = min(max(y1, 0), cap);
            float x0f = (float)x0, x1f = (float)x1;
            float y0f = (float)y0, y1f = (float)y1;

            float w00 = a * (x1f - x) * (y1f - y);
            float w01 = a * (x1f - x) * (y - y0f);
            float w10 = a * (x - x0f) * (y1f - y);
            float w11 = a * (x - x0f) * (y - y0f);
            if (y1 == y0) {        // y-clip: fold weight; padded row gets 0
                w00 += w01; w01 = 0.f;
                w10 += w11; w11 = 0.f;
            }
            swt[s][c] = make_float4(w00, w01, w10, w11);
            const int lb = cb + (LBASE_ROW[l] << 8) + h * plane32;
            int2 o;
            o.x = lb + (((x0 << lsh) + y0) << 5);
            o.y = lb + (((x1 << lsh) + y0) << 5);
            soff[s][c] = o;
        }
    }
    __syncthreads();   // offaw dead from here; sout takes over the union

    // ---- phase 4: gather: one wave per query; lane = (h, j) ----
    {
        // zero the dead A-rows (8..15) of the out-proj tile
        if (t < 264) {
            f16x8 z = {};
            ((f16x8*)&u.sout[QPB][0])[t] = z;
        }

        const int s    = w;
        const int h    = lane >> 3;
        const int j    = lane & 7;
        const int top  = j >> 2;        // 0: row y0, 1: row y1
        const int blk  = j & 3;         // dim block [8*blk .. 8*blk+7]

        float acc[8];
        #pragma unroll
        for (int k = 0; k < 8; ++k) acc[k] = 0.f;

        #pragma unroll 4
        for (int lp = 0; lp < NLP; ++lp) {
            const int c = lp * NH + h;
            int2   o = soff[s][c];
            float4 wt = swt[s][c];
            f16x8 va = *(const f16x8*)&Vc[o.x + j * 8];   // x0 pair
            f16x8 vb = *(const f16x8*)&Vc[o.y + j * 8];   // x1 pair
            const float wa = top ? wt.y : wt.x;
            const float wb = top ? wt.w : wt.z;
            #pragma unroll
            for (int k = 0; k < 8; ++k)
                acc[k] += wa * (float)va[k] + wb * (float)vb[k];
        }
        // lanes j and j^4 hold the same dim block for rows y0/y1 -> combine
        #pragma unroll
        for (int k = 0; k < 8; ++k)
            acc[k] += __shfl_xor(acc[k], 4);

        if (top == 0) {
            f16x8 o8;
            #pragma unroll
            for (int k = 0; k < 8; ++k) o8[k] = (__fp16)acc[k];
            *(f16x8*)&u.sout[s][h * HD + blk * 8] = o8;
        }
    }
    __syncthreads();

    // ---- phase 5: out-projection: out[q0..q0+7][:] = sout @ WoutT^T + b ---
    {
        const int mrow = lane & 15;
        const int quad = lane >> 4;

        const f16x8* B0 = (const f16x8*)(WoutT + (size_t)(w * 32 +  0 + mrow) * 256 + quad * 8);
        const f16x8* B1 = (const f16x8*)(WoutT + (size_t)(w * 32 + 16 + mrow) * 256 + quad * 8);

        f32x4 acc0 = {0.f,0.f,0.f,0.f}, acc1 = acc0;
        #pragma unroll
        for (int kb = 0; kb < 8; ++kb) {
            f16x8 af = *(const f16x8*)&u.sout[mrow][quad * 8 + kb * 32];
            acc0 = __builtin_amdgcn_mfma_f32_16x16x32_f16(af, B0[kb * 4], acc0, 0, 0, 0);
            acc1 = __builtin_amdgcn_mfma_f32_16x16x32_f16(af, B1[kb * 4], acc1, 0, 0, 0);
        }

        const int col = lane & 15;
        f32x4 accs[2] = {acc0, acc1};
        #pragma unroll
        for (int i = 0; i < 2; ++i) {
            int n = w * 32 + i * 16 + col;
            float bb = b_out[n];
            #pragma unroll
            for (int r = 0; r < 4; ++r) {
                int row = quad * 4 + r;
                if (row < QPB)
                    out[(size_t)(q0 + row) * ED + n] = accs[i][r] + bb;
            }
        }
    }
}

extern "C" void kernel_launch(void* const* d_in, const int* in_sizes, int n_in,
                              void* d_out, int out_size, void* d_ws, size_t ws_size,
                              hipStream_t stream) {
    const float* query  = (const float*)d_in[0];
    const float* refp   = (const float*)d_in[1];
    const float* V      = (const float*)d_in[2];
    const float* W_off  = (const float*)d_in[3];
    const float* b_off  = (const float*)d_in[4];
    const float* W_attn = (const float*)d_in[5];
    const float* b_attn = (const float*)d_in[6];
    const float* W_out  = (const float*)d_in[7];
    const float* b_out  = (const float*)d_in[8];
    const int*   boff   = (const int*)d_in[9];
    const int n_batch   = in_sizes[9];
    const int nq        = in_sizes[0] / ED;
    const int nb        = in_sizes[2] / BSTRIDE;
    float* out = (float*)d_out;

    // workspace layout (16B-aligned chunks); Vc tail pad covers the
    // (x=cap,y=cap) pair read that bleeds 64 B past the last row.
    char* ws = (char*)d_ws;
    __fp16*  WcatT = (__fp16*)ws;                // 384*256 f16
    __fp16*  WoutT = WcatT + NOFF_AW * ED;       // 256*256 f16
    __fp16*  Vc    = WoutT + ED * ED;            // nb*RPB*256 + pad

    // Kprep: V compaction (head-major) + weight conversion
    {
        int nCompact = (nb * RPB + 15) / 16;
        int nWconv   = (NOFF_AW * ED + ED * ED + 1023) / 1024;
        msda_prep_kernel<<<nCompact + nWconv, 1024, 0, stream>>>(
            V, W_off, W_attn, W_out, Vc, WcatT, WoutT, nb, nCompact);
    }
    // K2: fused GEMM + sampling + gather + out-projection -> out
    {
        msda_sample_kernel<<<nq / QPB, 512, 0, stream>>>(
            refp, Vc, query, WcatT, b_off, b_attn, boff, n_batch,
            WoutT, b_out, out, nq);
    }
}

// Round 3
// 256.154 us; speedup vs baseline: 1.0566x; 1.0566x over previous
//
#include <hip/hip_runtime.h>
#include <math.h>

#define ED      256       // EMBED_DIM
#define NL      4
#define NH      8
#define NP      4
#define HD      32        // HEAD_DIM
#define HMAX    128
#define WMAX    128
#define NLP     16        // NL*NP
#define NC      128       // NL*NP*NH
#define NOFF_AW 384       // 256 off cols + 128 attn cols
#define QPB     4         // queries per block in sampler
#define BSTRIDE (HMAX*WMAX*NL*ED)   // 16,777,216 elements
#define XSTRIDE (WMAX*NL*ED)        // 131,072
#define YSTRIDE (NL*ED)             // 1,024
#define RPB     21760               // compact rows per batch: 128^2+64^2+32^2+16^2
#define PBC     (RPB*256)           // compact elems per batch

typedef __attribute__((ext_vector_type(8))) __fp16   f16x8;
typedef __attribute__((ext_vector_type(4))) __fp16   f16x4;
typedef __attribute__((ext_vector_type(4))) float    f32x4;

__constant__ int LBASE_ROW[4] = {0, 16384, 20480, 21504};

// ---------------- Kw: weight transpose/convert (must precede Kmix GEMM) ---
__global__ __launch_bounds__(1024) void msda_wconv_kernel(
    const float* __restrict__ W_off,
    const float* __restrict__ W_attn,
    const float* __restrict__ W_out,
    __fp16* __restrict__ WcatT,
    __fp16* __restrict__ WoutT)
{
    const int idx = blockIdx.x * 1024 + threadIdx.x;
    const int t2 = NOFF_AW * ED;
    const int t3 = ED * ED;
    if (idx < t2) {
        int c = idx >> 8, e = idx & 255;
        float v = (c < ED) ? W_off[e * ED + c] : W_attn[e * NC + (c - ED)];
        WcatT[idx] = (__fp16)v;
    } else if (idx < t2 + t3) {
        int i = idx - t2;
        int c = i >> 8, e = i & 255;
        WoutT[i] = (__fp16)W_out[e * ED + c];
    }
}

// ---- Kmix: K1 GEMM blocks (first ngemm) + V-compaction blocks (rest) -----
// The two halves are data-independent (GEMM: query+WcatT -> off_aw;
// compaction: V -> Vc), so a single launch overlaps them: 192 GEMM blocks
// start on the first CUs while 2720 compaction blocks flood the rest --
// K1's ~10-15 us is no longer serially exposed.
//
// GEMM: C = (Ah+Al) @ WcatT^T + bias, 2-pass f16 (A exact), 16 waves/block,
// each wave one 16x64 tile.  Compaction: Vc head-major f16, 64-B rows;
// (x,y),(x,y+1) contiguous 128 B so a bilinear y-pair is one segment.
__global__ __launch_bounds__(1024) void msda_mix_kernel(
    const float* __restrict__ V,
    __fp16* __restrict__ Vc,
    const float* __restrict__ query,
    const __fp16* __restrict__ WcatT,
    const float* __restrict__ b_off,
    const float* __restrict__ b_attn,
    float* __restrict__ off_aw,
    int nb, int ngemm, int M)
{
    const int bid  = blockIdx.x;
    const int wave = threadIdx.x >> 6;
    const int lane = threadIdx.x & 63;

    if (bid < ngemm) {
        // ---------------- K1 GEMM path ----------------
        const int gw = bid * 16 + wave;
        const int ngroups = NOFF_AW >> 6;          // 6
        const int mg = gw / ngroups, ng = gw % ngroups;
        const int m16 = mg * 16, n64 = ng * 64;
        if (m16 >= M) return;

        const int mrow = lane & 15;
        const int quad = lane >> 4;

        const float4* Arow = (const float4*)(query + (size_t)(m16 + mrow) * 256 + quad * 8);
        const f16x8* B0 = (const f16x8*)(WcatT + (size_t)(n64 +  0 + mrow) * 256 + quad * 8);
        const f16x8* B1 = (const f16x8*)(WcatT + (size_t)(n64 + 16 + mrow) * 256 + quad * 8);
        const f16x8* B2 = (const f16x8*)(WcatT + (size_t)(n64 + 32 + mrow) * 256 + quad * 8);
        const f16x8* B3 = (const f16x8*)(WcatT + (size_t)(n64 + 48 + mrow) * 256 + quad * 8);

        f32x4 acc0 = {0.f,0.f,0.f,0.f}, acc1 = acc0, acc2 = acc0, acc3 = acc0;
        #pragma unroll
        for (int kb = 0; kb < 8; ++kb) {
            float4 a0 = Arow[kb * 8 + 0];
            float4 a1 = Arow[kb * 8 + 1];
            float av[8] = {a0.x, a0.y, a0.z, a0.w, a1.x, a1.y, a1.z, a1.w};
            f16x8 ah, al;
            #pragma unroll
            for (int j = 0; j < 8; ++j) {
                __fp16 h = (__fp16)av[j];
                ah[j] = h;
                al[j] = (__fp16)(av[j] - (float)h);
            }
            f16x8 b0 = B0[kb * 4], b1 = B1[kb * 4], b2 = B2[kb * 4], b3 = B3[kb * 4];
            acc0 = __builtin_amdgcn_mfma_f32_16x16x32_f16(ah, b0, acc0, 0, 0, 0);
            acc1 = __builtin_amdgcn_mfma_f32_16x16x32_f16(ah, b1, acc1, 0, 0, 0);
            acc2 = __builtin_amdgcn_mfma_f32_16x16x32_f16(ah, b2, acc2, 0, 0, 0);
            acc3 = __builtin_amdgcn_mfma_f32_16x16x32_f16(ah, b3, acc3, 0, 0, 0);
            acc0 = __builtin_amdgcn_mfma_f32_16x16x32_f16(al, b0, acc0, 0, 0, 0);
            acc1 = __builtin_amdgcn_mfma_f32_16x16x32_f16(al, b1, acc1, 0, 0, 0);
            acc2 = __builtin_amdgcn_mfma_f32_16x16x32_f16(al, b2, acc2, 0, 0, 0);
            acc3 = __builtin_amdgcn_mfma_f32_16x16x32_f16(al, b3, acc3, 0, 0, 0);
        }

        const int col = lane & 15;
        f32x4 accs[4] = {acc0, acc1, acc2, acc3};
        #pragma unroll
        for (int i = 0; i < 4; ++i) {
            int n = n64 + i * 16 + col;
            float b = (n < ED) ? b_off[n] : b_attn[n - ED];
            #pragma unroll
            for (int r = 0; r < 4; ++r) {
                int row = m16 + quad * 4 + r;
                off_aw[(size_t)row * NOFF_AW + n] = accs[i][r] + b;
            }
        }
    } else {
        // ---------------- V-compaction path ----------------
        const int r = (bid - ngemm) * 16 + wave;
        const int h    = lane >> 3;
        const int j4   = lane & 7;
        const int total_rows = nb * RPB;
        if (r < total_rows) {
            const int b  = r / RPB;
            const int rr = r - b * RPB;
            int l;
            if (rr < 16384)      { l = 0; }
            else if (rr < 20480) { l = 1; }
            else if (rr < 21504) { l = 2; }
            else                 { l = 3; }
            const int pos = rr - LBASE_ROW[l];    // x*sz + y within level
            const int lsh = 7 - l;
            const int xi  = pos >> lsh;
            const int yi  = pos & ((1 << lsh) - 1);
            const int plane32 = (1 << (2 * lsh)) * 32;   // per-head plane elems
            const float4 src = *(const float4*)&V[(size_t)b * BSTRIDE +
                (size_t)xi * XSTRIDE + (size_t)yi * YSTRIDE + l * ED +
                h * HD + j4 * 4];
            f16x4 d;
            d[0] = (__fp16)src.x; d[1] = (__fp16)src.y;
            d[2] = (__fp16)src.z; d[3] = (__fp16)src.w;
            const size_t dst = (size_t)b * PBC + (size_t)LBASE_ROW[l] * 256 +
                               (size_t)h * plane32 + (size_t)pos * 32 + j4 * 4;
            *(f16x4*)&Vc[dst] = d;
        }
    }
}

// ---------------- K2: softmax + sampling + PAIRED bilinear gather ---------
__global__ __launch_bounds__(256) void msda_sample_kernel(
    const float*  __restrict__ refp,     // (Q, 2)
    const __fp16* __restrict__ Vc,       // compact head-major f16 V
    const float*  __restrict__ off_aw,   // (Q, 384)
    const int*    __restrict__ batch_off,
    int n_batch,
    __fp16* __restrict__ out_pre,        // (Q, 256) f16
    int q_total)
{
    __shared__ float  law[QPB][NC];
    __shared__ float2 sminv[QPB][NH];
    __shared__ float2 sref[QPB];
    __shared__ int2   soff[QPB][NC];     // pairA (x0), pairB (x1) elem offsets
    __shared__ float4 swt[QPB][NC];      // folded w00,w01,w10,w11

    const int t  = threadIdx.x;
    const int q0 = blockIdx.x * QPB;

    // ---- load attn logits ----
    {
        const int s = t >> 6, c = t & 63;
        const float* row = off_aw + (size_t)(q0 + s) * NOFF_AW + ED;
        law[s][c]      = row[c];
        law[s][c + 64] = row[c + 64];
    }
    __syncthreads();

    // ---- softmax stats + ref-point prep ----
    if (t < QPB * NH) {
        const int s = t >> 3, h = t & 7;
        float m = -1e30f;
        #pragma unroll
        for (int lp = 0; lp < NLP; ++lp) m = fmaxf(m, law[s][lp * NH + h]);
        float sum = 0.f;
        #pragma unroll
        for (int lp = 0; lp < NLP; ++lp) sum += __expf(law[s][lp * NH + h] - m);
        sminv[s][h] = make_float2(m, 1.f / sum);
    } else if (t < QPB * NH + QPB) {
        const int s = t - QPB * NH;
        const int qid = q0 + s;
        float rx = refp[qid * 2 + 0], ry = refp[qid * 2 + 1];
        rx = fminf(fmaxf(rx, 0.f), 1.f);
        ry = fminf(fmaxf(ry, 0.f), 1.f);
        float ivx = __logf(fmaxf(rx, 1e-5f) / fmaxf(1.f - rx, 1e-5f));
        float ivy = __logf(fmaxf(ry, 1e-5f) / fmaxf(1.f - ry, 1e-5f));
        sref[s] = make_float2(ivx, ivy);
    }
    __syncthreads();

    // ---- sampling params: pair offsets + folded weights ----
    {
        const int s = t >> 6;
        const int qid = q0 + s;
        int b = 0;
        for (int i = 1; i < n_batch; ++i)
            if (batch_off[i] <= qid) b = i;
        const int cb = b * PBC;
        const float2 iv = sref[s];
        const float* offrow = off_aw + (size_t)qid * NOFF_AW;

        #pragma unroll
        for (int half = 0; half < 2; ++half) {
            const int c = (t & 63) + half * 64;
            const int l = c >> 5;
            const int lsh = 7 - l;
            const int sz  = 1 << lsh;
            const int cap = sz - 1;
            const int h = c & 7;
            const int plane32 = (sz * sz) << 5;

            const float2 mi = sminv[s][h];
            const float a = __expf(law[s][c] - mi.x) * mi.y;

            const float ox = offrow[c * 2 + 0], oy = offrow[c * 2 + 1];
            float lx = 2.f / (1.f + __expf(-(iv.x + ox))) - 1.f;
            float ly = 2.f / (1.f + __expf(-(iv.y + oy))) - 1.f;
            float x = ((lx + 1.f) * (float)sz - 1.f) * 0.5f;
            float y = ((ly + 1.f) * (float)sz - 1.f) * 0.5f;
            int x0 = (int)floorf(x), y0 = (int)floorf(y);
            int x1 = x0 + 1, y1 = y0 + 1;
            x0 = min(max(x0, 0), cap); x1 = min(max(x1, 0), cap);
            y0 = min(max(y0, 0), cap); y1 = min(max(y1, 0), cap);
            float x0f = (float)x0, x1f = (float)x1;
            float y0f = (float)y0, y1f = (float)y1;

            float w00 = a * (x1f - x) * (y1f - y);
            float w01 = a * (x1f - x) * (y - y0f);
            float w10 = a * (x - x0f) * (y1f - y);
            float w11 = a * (x - x0f) * (y - y0f);
            if (y1 == y0) {        // y-clip: fold weight; padded row gets 0
                w00 += w01; w01 = 0.f;
                w10 += w11; w11 = 0.f;
            }
            swt[s][c] = make_float4(w00, w01, w10, w11);
            const int lb = cb + (LBASE_ROW[l] << 8) + h * plane32;
            int2 o;
            o.x = lb + (((x0 << lsh) + y0) << 5);
            o.y = lb + (((x1 << lsh) + y0) << 5);
            soff[s][c] = o;
        }
    }
    __syncthreads();

    // ---- gather: one wave per query; lane = (h, j); paired f16x8 loads ---
    {
        const int s    = t >> 6;
        const int lane = t & 63;
        const int h    = lane >> 3;
        const int j    = lane & 7;
        const int top  = j >> 2;        // 0: row y0, 1: row y1
        const int blk  = j & 3;         // dim block [8*blk .. 8*blk+7]

        float acc[8];
        #pragma unroll
        for (int k = 0; k < 8; ++k) acc[k] = 0.f;

        #pragma unroll 4
        for (int lp = 0; lp < NLP; ++lp) {
            const int c = lp * NH + h;
            int2   o = soff[s][c];
            float4 w = swt[s][c];
            f16x8 va = *(const f16x8*)&Vc[o.x + j * 8];   // x0 pair
            f16x8 vb = *(const f16x8*)&Vc[o.y + j * 8];   // x1 pair
            const float wa = top ? w.y : w.x;
            const float wb = top ? w.w : w.z;
            #pragma unroll
            for (int k = 0; k < 8; ++k)
                acc[k] += wa * (float)va[k] + wb * (float)vb[k];
        }
        // lanes j and j^4 hold the same dim block for rows y0/y1 -> combine
        #pragma unroll
        for (int k = 0; k < 8; ++k)
            acc[k] += __shfl_xor(acc[k], 4);

        if (top == 0) {
            f16x8 o8;
            #pragma unroll
            for (int k = 0; k < 8; ++k) o8[k] = (__fp16)acc[k];
            *(f16x8*)&out_pre[(size_t)(q0 + s) * ED + h * HD + blk * 8] = o8;
        }
    }
}

// ---------------- K3: plain f16 MFMA GEMM ---------------------------------
__global__ __launch_bounds__(256) void gemm_ff16_kernel(
    const __fp16* __restrict__ A,     // (M,256) f16
    const __fp16* __restrict__ BT,    // (NTOT,256) f16
    const float* __restrict__ bias,
    float* __restrict__ C,
    int M, int NTOT)
{
    const int wave = threadIdx.x >> 6;
    const int lane = threadIdx.x & 63;
    const int gw   = blockIdx.x * 4 + wave;
    const int ngroups = NTOT >> 6;
    const int mg = gw / ngroups, ng = gw % ngroups;
    const int m16 = mg * 16, n64 = ng * 64;
    if (m16 >= M) return;

    const int mrow = lane & 15;
    const int quad = lane >> 4;

    const f16x8* Arow = (const f16x8*)(A + (size_t)(m16 + mrow) * 256 + quad * 8);
    const f16x8* B0 = (const f16x8*)(BT + (size_t)(n64 +  0 + mrow) * 256 + quad * 8);
    const f16x8* B1 = (const f16x8*)(BT + (size_t)(n64 + 16 + mrow) * 256 + quad * 8);
    const f16x8* B2 = (const f16x8*)(BT + (size_t)(n64 + 32 + mrow) * 256 + quad * 8);
    const f16x8* B3 = (const f16x8*)(BT + (size_t)(n64 + 48 + mrow) * 256 + quad * 8);

    f32x4 acc0 = {0.f,0.f,0.f,0.f}, acc1 = acc0, acc2 = acc0, acc3 = acc0;
    #pragma unroll
    for (int kb = 0; kb < 8; ++kb) {
        f16x8 af = Arow[kb * 4];
        acc0 = __builtin_amdgcn_mfma_f32_16x16x32_f16(af, B0[kb * 4], acc0, 0, 0, 0);
        acc1 = __builtin_amdgcn_mfma_f32_16x16x32_f16(af, B1[kb * 4], acc1, 0, 0, 0);
        acc2 = __builtin_amdgcn_mfma_f32_16x16x32_f16(af, B2[kb * 4], acc2, 0, 0, 0);
        acc3 = __builtin_amdgcn_mfma_f32_16x16x32_f16(af, B3[kb * 4], acc3, 0, 0, 0);
    }

    const int col = lane & 15;
    f32x4 accs[4] = {acc0, acc1, acc2, acc3};
    #pragma unroll
    for (int i = 0; i < 4; ++i) {
        int n = n64 + i * 16 + col;
        float b = bias[n];
        #pragma unroll
        for (int r = 0; r < 4; ++r) {
            int row = m16 + quad * 4 + r;
            C[(size_t)row * NTOT + n] = accs[i][r] + b;
        }
    }
}

extern "C" void kernel_launch(void* const* d_in, const int* in_sizes, int n_in,
                              void* d_out, int out_size, void* d_ws, size_t ws_size,
                              hipStream_t stream) {
    const float* query  = (const float*)d_in[0];
    const float* refp   = (const float*)d_in[1];
    const float* V      = (const float*)d_in[2];
    const float* W_off  = (const float*)d_in[3];
    const float* b_off  = (const float*)d_in[4];
    const float* W_attn = (const float*)d_in[5];
    const float* b_attn = (const float*)d_in[6];
    const float* W_out  = (const float*)d_in[7];
    const float* b_out  = (const float*)d_in[8];
    const int*   boff   = (const int*)d_in[9];
    const int n_batch   = in_sizes[9];
    const int nq        = in_sizes[0] / ED;
    const int nb        = in_sizes[2] / BSTRIDE;
    float* out = (float*)d_out;

    // workspace layout (16B-aligned chunks); Vc tail pad covers the
    // (x=cap,y=cap) pair read that bleeds 64 B past the last row.
    char* ws = (char*)d_ws;
    float*   off_aw  = (float*)ws;                              // nq*384 f32
    __fp16*  WcatT   = (__fp16*)(off_aw + (size_t)nq * NOFF_AW);// 384*256 f16
    __fp16*  WoutT   = WcatT + NOFF_AW * ED;                    // 256*256 f16
    __fp16*  out_pre = WoutT + ED * ED;                         // nq*256 f16
    __fp16*  Vc      = out_pre + (size_t)nq * ED;               // nb*RPB*256+pad

    // Kw: weight transpose/convert (WcatT needed by Kmix's GEMM half)
    {
        int nWconv = (NOFF_AW * ED + ED * ED + 1023) / 1024;
        msda_wconv_kernel<<<nWconv, 1024, 0, stream>>>(
            W_off, W_attn, W_out, WcatT, WoutT);
    }
    // Kmix: K1 GEMM (first 192 blocks) overlapped with V compaction (rest)
    {
        int ngemm    = ((nq / 16) * (NOFF_AW / 64) + 15) / 16;
        int nCompact = (nb * RPB + 15) / 16;
        msda_mix_kernel<<<ngemm + nCompact, 1024, 0, stream>>>(
            V, Vc, query, WcatT, b_off, b_attn, off_aw, nb, ngemm, nq);
    }
    // K2: sampling + paired gather -> out_pre
    {
        msda_sample_kernel<<<nq / QPB, 256, 0, stream>>>(
            refp, Vc, off_aw, boff, n_batch, out_pre, nq);
    }
    // K3: out = out_pre @ W_out + b_out
    {
        int waves = (nq / 16) * (ED / 64);
        gemm_ff16_kernel<<<(waves + 3) / 4, 256, 0, stream>>>(
            out_pre, WoutT, b_out, out, nq, ED);
    }
}